// Round 4
// baseline (433.607 us; speedup 1.0000x reference)
//
#include <hip/hip_runtime.h>
#include <hip/hip_bf16.h>

#define H 20
#define Q 32
#define D 64
#define NSTATE 1280
#define CACHE_N 16384
#define NSPLIT 32
#define KCHUNK (CACHE_N / NSPLIT)   // 512 rows per split
#define TK 64                        // rows per tile

typedef __attribute__((ext_vector_type(4))) float f32x4;

// ---------------------------------------------------------------------------
// Full-K tiled GEMM: out[32,1280] = x[32,1280] @ W[1280,1280]^T (+ bias)
// One block per 64-col strip; K=1280 walked in 20 tiles of 64 with register
// double-buffering (loads for tile kt+1 issued before compute on tile kt).
// No atomics, no memset dependency: every output written exactly once.
// NOTE: unroll pragmas are load-bearing — full unroll spilled past 256 VGPRs
// and generated 1 GB of scratch traffic (653 us) in round 1.
// ---------------------------------------------------------------------------
__device__ __forceinline__ void gemm_fullk(const float* __restrict__ x,
                                           const float* __restrict__ W,
                                           const float* __restrict__ bias,
                                           float* __restrict__ out, int c0) {
    __shared__ float xs[2][64][36];   // [buf][k][row]  x^T tile
    __shared__ float wt[2][64][66];   // [buf][k][col]  W^T tile
    const int t  = threadIdx.x;
    const int rt = t >> 5;            // 0..7  -> rows rt*4..rt*4+3
    const int ct = t & 31;            // 0..31 -> cols ct*2..ct*2+1
    float acc[4][2] = {};
    float4 px[2], pw[4];

    // load tile 0 into registers
#pragma unroll
    for (int p = 0; p < 2; ++p) {
        int idx = t + p * 256, r = idx >> 4, c4 = idx & 15;
        px[p] = *(const float4*)(x + r * NSTATE + c4 * 4);
    }
#pragma unroll
    for (int p = 0; p < 4; ++p) {
        int idx = t + p * 256, c = idx >> 4, c4 = idx & 15;
        pw[p] = *(const float4*)(W + (long long)(c0 + c) * NSTATE + c4 * 4);
    }
    // store tile 0 into buffer 0
#pragma unroll
    for (int p = 0; p < 2; ++p) {
        int idx = t + p * 256, r = idx >> 4, c4 = idx & 15;
        xs[0][c4 * 4 + 0][r] = px[p].x; xs[0][c4 * 4 + 1][r] = px[p].y;
        xs[0][c4 * 4 + 2][r] = px[p].z; xs[0][c4 * 4 + 3][r] = px[p].w;
    }
#pragma unroll
    for (int p = 0; p < 4; ++p) {
        int idx = t + p * 256, c = idx >> 4, c4 = idx & 15;
        wt[0][c4 * 4 + 0][c] = pw[p].x; wt[0][c4 * 4 + 1][c] = pw[p].y;
        wt[0][c4 * 4 + 2][c] = pw[p].z; wt[0][c4 * 4 + 3][c] = pw[p].w;
    }
    __syncthreads();

#pragma unroll 1
    for (int kt = 0; kt < NSTATE / 64; ++kt) {
        const int buf = kt & 1;
        if (kt + 1 < NSTATE / 64) {      // issue next tile's global loads
            const int k0 = (kt + 1) * 64;
#pragma unroll
            for (int p = 0; p < 2; ++p) {
                int idx = t + p * 256, r = idx >> 4, c4 = idx & 15;
                px[p] = *(const float4*)(x + r * NSTATE + k0 + c4 * 4);
            }
#pragma unroll
            for (int p = 0; p < 4; ++p) {
                int idx = t + p * 256, c = idx >> 4, c4 = idx & 15;
                pw[p] = *(const float4*)(W + (long long)(c0 + c) * NSTATE + k0 + c4 * 4);
            }
        }
        // compute on current buffer
#pragma unroll 8
        for (int kk = 0; kk < 64; ++kk) {
            float4 xv = *(const float4*)&xs[buf][kk][rt * 4];
            float2 wv = *(const float2*)&wt[buf][kk][ct * 2];
            acc[0][0] += xv.x * wv.x; acc[0][1] += xv.x * wv.y;
            acc[1][0] += xv.y * wv.x; acc[1][1] += xv.y * wv.y;
            acc[2][0] += xv.z * wv.x; acc[2][1] += xv.z * wv.y;
            acc[3][0] += xv.w * wv.x; acc[3][1] += xv.w * wv.y;
        }
        if (kt + 1 < NSTATE / 64) {      // store prefetched tile to other buffer
            const int nb = buf ^ 1;
#pragma unroll
            for (int p = 0; p < 2; ++p) {
                int idx = t + p * 256, r = idx >> 4, c4 = idx & 15;
                xs[nb][c4 * 4 + 0][r] = px[p].x; xs[nb][c4 * 4 + 1][r] = px[p].y;
                xs[nb][c4 * 4 + 2][r] = px[p].z; xs[nb][c4 * 4 + 3][r] = px[p].w;
            }
#pragma unroll
            for (int p = 0; p < 4; ++p) {
                int idx = t + p * 256, c = idx >> 4, c4 = idx & 15;
                wt[nb][c4 * 4 + 0][c] = pw[p].x; wt[nb][c4 * 4 + 1][c] = pw[p].y;
                wt[nb][c4 * 4 + 2][c] = pw[p].z; wt[nb][c4 * 4 + 3][c] = pw[p].w;
            }
        }
        __syncthreads();
    }
#pragma unroll
    for (int r = 0; r < 4; ++r) {
        int i = rt * 4 + r;
#pragma unroll
        for (int cc = 0; cc < 2; ++cc) {
            int c = c0 + ct * 2 + cc;
            out[i * NSTATE + c] = acc[r][cc] + (bias ? bias[c] : 0.f);
        }
    }
}

__global__ __launch_bounds__(256)
void gemm_qkv(const float* __restrict__ x,
              const float* __restrict__ Wq, const float* __restrict__ bq,
              const float* __restrict__ Wk,
              const float* __restrict__ Wv, const float* __restrict__ bv,
              float* __restrict__ q, float* __restrict__ k, float* __restrict__ v) {
    const int mat = blockIdx.y;
    const float* W; const float* bias; float* out;
    if (mat == 0)      { W = Wq; bias = bq;      out = q; }
    else if (mat == 1) { W = Wk; bias = nullptr; out = k; }
    else               { W = Wv; bias = bv;      out = v; }
    gemm_fullk(x, W, bias, out, blockIdx.x * 64);
}

__global__ __launch_bounds__(256)
void gemm_one(const float* __restrict__ x, const float* __restrict__ W,
              const float* __restrict__ bias, float* __restrict__ out) {
    gemm_fullk(x, W, bias, out, blockIdx.x * 64);
}

// rowmap[j] = i if positions[i] == j else -1. Self-initializing (no memset).
__global__ void build_rowmap(const int* __restrict__ pos, int* __restrict__ rowmap) {
    const int t = threadIdx.x;
    for (int j = t; j < CACHE_N; j += 256) rowmap[j] = -1;
    __syncthreads();
    if (t < Q) rowmap[pos[t]] = t;
}

// ---------------------------------------------------------------------------
// FUSED: cache-update write-through + flash-decoding attention partials.
// grid (NSPLIT, H). Block (sp,h) streams rows [sp*512,(sp+1)*512) x cols
// [h*64,(h+1)*64) of K and V from the input caches (with rowmap replacement
// from the fresh projections), writes them to the output caches (nontemporal
// — written once, never re-read), and runs QK^T -> online softmax -> PV.
// launch_bounds(256,3): LDS 53.4 KB allows 3 blocks/CU -> all 640 resident.
// ---------------------------------------------------------------------------
__global__ __launch_bounds__(256, 3)
void attn_fused(const float* __restrict__ qw,
                const float* __restrict__ kci, const float* __restrict__ vci,
                const float* __restrict__ knew, const float* __restrict__ vnew,
                const int* __restrict__ rowmap, const float* __restrict__ mask,
                float* __restrict__ kc, float* __restrict__ vc,
                float* __restrict__ mpart, float* __restrict__ lpart,
                __hip_bfloat16* __restrict__ opart) {
    const int h  = blockIdx.y;
    const int sp = blockIdx.x;
    const int j_base = sp * KCHUNK;

    __shared__ float qs[D][36];       // q^T (scaled): qs[d][i]
    __shared__ float ks_[D][66];      // K^T tile: ks_[d][j]
    __shared__ float vs[TK][68];      // V tile:   vs[j][d]
    __shared__ float ps[TK][36];      // P^T tile: ps[j][i]
    __shared__ float m_s[Q], l_s[Q], alpha_s[Q], tmax[Q], tsum[Q];

    const int t = threadIdx.x;
    const int qt = t >> 5;            // 0..7 : 4 queries each
    const int kt = t & 31;            // 0..31: 2 keys each (QK stage)
    const int dt = t & 31;            // 0..31: 2 dims each (PV stage)

    // stage q for this head, fold in scale = 1/sqrt(64) = 0.125
#pragma unroll
    for (int p = 0; p < 2; ++p) {
        int idx = t + p * 256;
        int i = idx >> 4, c4 = idx & 15;
        float4 v4 = *(const float4*)(qw + i * NSTATE + h * D + c4 * 4);
        const float sc = 0.125f;
        qs[c4 * 4 + 0][i] = v4.x * sc; qs[c4 * 4 + 1][i] = v4.y * sc;
        qs[c4 * 4 + 2][i] = v4.z * sc; qs[c4 * 4 + 3][i] = v4.w * sc;
    }
    if (t < Q) { m_s[t] = -1e30f; l_s[t] = 0.f; }
    float oacc[4][2] = {};
    __syncthreads();

#pragma unroll 1
    for (int tile = 0; tile < KCHUNK / TK; ++tile) {
        const int j0 = j_base + tile * TK;
        __syncthreads();   // protect LDS from previous tile's readers
        // stage K/V tile (64 rows x 64 cols each) with row replacement,
        // write-through to the output caches.
#pragma unroll
        for (int p = 0; p < 4; ++p) {
            int idx = t + p * 256;                 // 0..1023
            int row = idx >> 4, c4 = idx & 15;
            long long j = j0 + row;
            int src = rowmap[j];
            const float* kb; const float* vb;
            if (src >= 0) { kb = knew + (long long)src * NSTATE; vb = vnew + (long long)src * NSTATE; }
            else          { kb = kci + j * NSTATE;               vb = vci + j * NSTATE; }
            float4 k4 = *(const float4*)(kb + h * D + c4 * 4);
            float4 v4 = *(const float4*)(vb + h * D + c4 * 4);
            __builtin_nontemporal_store(*(const f32x4*)&k4, (f32x4*)(kc + j * NSTATE + h * D + c4 * 4));
            __builtin_nontemporal_store(*(const f32x4*)&v4, (f32x4*)(vc + j * NSTATE + h * D + c4 * 4));
            ks_[c4 * 4 + 0][row] = k4.x; ks_[c4 * 4 + 1][row] = k4.y;
            ks_[c4 * 4 + 2][row] = k4.z; ks_[c4 * 4 + 3][row] = k4.w;
            *(float4*)&vs[row][c4 * 4] = v4;
        }
        __syncthreads();

        // QK^T: 4q x 2k per thread
        float s[4][2] = {};
#pragma unroll 8
        for (int d = 0; d < D; ++d) {
            float4 qv = *(const float4*)&qs[d][qt * 4];
            float2 kv = *(const float2*)&ks_[d][kt * 2];
            s[0][0] += qv.x * kv.x; s[0][1] += qv.x * kv.y;
            s[1][0] += qv.y * kv.x; s[1][1] += qv.y * kv.y;
            s[2][0] += qv.z * kv.x; s[2][1] += qv.z * kv.y;
            s[3][0] += qv.w * kv.x; s[3][1] += qv.w * kv.y;
        }
        // + mask
#pragma unroll
        for (int r = 0; r < 4; ++r) {
            int i = qt * 4 + r;
            float2 mv = *(const float2*)(mask + (long long)i * CACHE_N + j0 + kt * 2);
            s[r][0] += mv.x; s[r][1] += mv.y;
        }
        // per-query tile max
        float rmax[4];
#pragma unroll
        for (int r = 0; r < 4; ++r) rmax[r] = fmaxf(s[r][0], s[r][1]);
#pragma unroll
        for (int off = 16; off >= 1; off >>= 1)
#pragma unroll
            for (int r = 0; r < 4; ++r)
                rmax[r] = fmaxf(rmax[r], __shfl_xor(rmax[r], off, 64));
        if (kt == 0)
#pragma unroll
            for (int r = 0; r < 4; ++r) tmax[qt * 4 + r] = rmax[r];
        __syncthreads();
        if (t < Q) {
            float mo = m_s[t], mn = fmaxf(mo, tmax[t]);
            float a = __expf(mo - mn);
            m_s[t] = mn; alpha_s[t] = a; l_s[t] *= a;
        }
        __syncthreads();
        // p = exp(s - m_new); write P^T; per-query partial sums
        float pr[4][2], rsum[4];
#pragma unroll
        for (int r = 0; r < 4; ++r) {
            float mn = m_s[qt * 4 + r];
            pr[r][0] = __expf(s[r][0] - mn);
            pr[r][1] = __expf(s[r][1] - mn);
            rsum[r] = pr[r][0] + pr[r][1];
        }
#pragma unroll
        for (int c = 0; c < 2; ++c)
            *(float4*)&ps[kt * 2 + c][qt * 4] =
                make_float4(pr[0][c], pr[1][c], pr[2][c], pr[3][c]);
#pragma unroll
        for (int off = 16; off >= 1; off >>= 1)
#pragma unroll
            for (int r = 0; r < 4; ++r)
                rsum[r] += __shfl_xor(rsum[r], off, 64);
        if (kt == 0)
#pragma unroll
            for (int r = 0; r < 4; ++r) tsum[qt * 4 + r] = rsum[r];
        // rescale running output
        {
            float a0 = alpha_s[qt * 4 + 0], a1 = alpha_s[qt * 4 + 1];
            float a2 = alpha_s[qt * 4 + 2], a3 = alpha_s[qt * 4 + 3];
            oacc[0][0] *= a0; oacc[0][1] *= a0;
            oacc[1][0] *= a1; oacc[1][1] *= a1;
            oacc[2][0] *= a2; oacc[2][1] *= a2;
            oacc[3][0] *= a3; oacc[3][1] *= a3;
        }
        __syncthreads();
        if (t < Q) l_s[t] += tsum[t];
        // PV: 4q x 2d per thread
#pragma unroll 8
        for (int j = 0; j < TK; ++j) {
            float4 pv = *(const float4*)&ps[j][qt * 4];
            float2 vv = *(const float2*)&vs[j][dt * 2];
            oacc[0][0] += pv.x * vv.x; oacc[0][1] += pv.x * vv.y;
            oacc[1][0] += pv.y * vv.x; oacc[1][1] += pv.y * vv.y;
            oacc[2][0] += pv.z * vv.x; oacc[2][1] += pv.z * vv.y;
            oacc[3][0] += pv.w * vv.x; oacc[3][1] += pv.w * vv.y;
        }
    }
    __syncthreads();
    const int pb = (h * NSPLIT + sp) * Q;
    if (t < Q) { mpart[pb + t] = m_s[t]; lpart[pb + t] = l_s[t]; }
#pragma unroll
    for (int r = 0; r < 4; ++r) {
        int i = qt * 4 + r;
        __hip_bfloat16 hx = __float2bfloat16(oacc[r][0]);
        __hip_bfloat16 hy = __float2bfloat16(oacc[r][1]);
        ushort2 u = make_ushort2(*(unsigned short*)&hx, *(unsigned short*)&hy);
        *(ushort2*)((unsigned short*)opart + (size_t)(pb + i) * D + dt * 2) = u;
    }
}

// Combine split partials -> attention output [32,1280]
__global__ __launch_bounds__(64)
void attn_combine(const float* __restrict__ mpart, const float* __restrict__ lpart,
                  const __hip_bfloat16* __restrict__ opart, float* __restrict__ oattn) {
    const int i = blockIdx.x;   // query
    const int h = blockIdx.y;   // head
    const int d = threadIdx.x;  // dim
    float m[NSPLIT];
    float gm = -1e30f;
#pragma unroll
    for (int s = 0; s < NSPLIT; ++s) {
        m[s] = mpart[(h * NSPLIT + s) * Q + i];
        gm = fmaxf(gm, m[s]);
    }
    float l = 0.f, o = 0.f;
#pragma unroll
    for (int s = 0; s < NSPLIT; ++s) {
        float w = __expf(m[s] - gm);
        l += lpart[(h * NSPLIT + s) * Q + i] * w;
        o += __bfloat162float(opart[(size_t)((h * NSPLIT + s) * Q + i) * D + d]) * w;
    }
    oattn[i * NSTATE + h * D + d] = o / l;
}

// ---------------------------------------------------------------------------
extern "C" void kernel_launch(void* const* d_in, const int* in_sizes, int n_in,
                              void* d_out, int out_size, void* d_ws, size_t ws_size,
                              hipStream_t stream) {
    const float* x    = (const float*)d_in[0];
    const float* kci  = (const float*)d_in[1];
    const float* vci  = (const float*)d_in[2];
    const int*   pos  = (const int*)d_in[3];
    const float* mask = (const float*)d_in[4];
    const float* Wq   = (const float*)d_in[5];
    const float* bq   = (const float*)d_in[6];
    const float* Wk   = (const float*)d_in[7];
    const float* Wv   = (const float*)d_in[8];
    const float* bv   = (const float*)d_in[9];
    const float* Wout = (const float*)d_in[10];
    const float* bout = (const float*)d_in[11];

    float* out  = (float*)d_out;                 // [32*1280]
    float* kc   = out + 40960;                   // [16384*1280]
    float* vc   = kc + CACHE_N * NSTATE;

    // workspace layout (float offsets); total 3,342,336 B (proven safe).
    float* ws      = (float*)d_ws;
    float* kws     = ws;                          // 40960
    float* vws     = ws + 40960;                  // 40960
    float* qws     = ws + 81920;                  // 40960 (reused as oattn)
    float* mpart   = ws + 122880;                 // 20480
    float* lpart   = ws + 143360;                 // 20480
    int*   rowmap  = (int*)(ws + 163840);         // 16384 ints
    __hip_bfloat16* opart = (__hip_bfloat16*)(ws + 180224);  // 1,310,720 bf16
    float* oattn   = qws;

    build_rowmap<<<1, 256, 0, stream>>>(pos, rowmap);

    // 1. q/k/v projections (full-K, direct writes)
    gemm_qkv<<<dim3(NSTATE / 64, 3), 256, 0, stream>>>(x, Wq, bq, Wk, Wv, bv, qws, kws, vws);

    // 2. fused cache-update + attention partials
    attn_fused<<<dim3(NSPLIT, H), 256, 0, stream>>>(qws, kci, vci, kws, vws, rowmap, mask,
                                                    kc, vc, mpart, lpart, opart);

    // 3. combine splits
    attn_combine<<<dim3(Q, H), 64, 0, stream>>>(mpart, lpart, opart, oattn);

    // 4. output projection
    gemm_one<<<NSTATE / 64, 256, 0, stream>>>(oattn, Wout, bout, out);
}